// Round 9
// baseline (485.692 us; speedup 1.0000x reference)
//
#include <hip/hip_runtime.h>
#include <hip/hip_bf16.h>

typedef __bf16 bf16x8 __attribute__((ext_vector_type(8)));
typedef __bf16 bf16x4 __attribute__((ext_vector_type(4)));
typedef float f32x4 __attribute__((ext_vector_type(4)));

#define GLOBAL_LOAD_LDS16(gp, lp)                                              \
  __builtin_amdgcn_global_load_lds(                                            \
      (const __attribute__((address_space(1))) void*)(gp),                     \
      (__attribute__((address_space(3))) void*)(lp), 16, 0, 0)

// ---------------------------------------------------------------------------
// Prep kernels (one-time, bandwidth-bound)
// ---------------------------------------------------------------------------
__global__ __launch_bounds__(256) void transpose4_f2b_k(
    const float* __restrict__ s0, const float* __restrict__ s1,
    const float* __restrict__ s2, const float* __restrict__ s3,
    __bf16* __restrict__ dst) {
  __shared__ float tile[32][33];
  const float* srcs[4] = {s0, s1, s2, s3};
  const float* src = srcs[blockIdx.z];
  __bf16* d = dst + ((size_t)blockIdx.z << 20);
  const int bx = blockIdx.x * 32, by = blockIdx.y * 32;
  const int tx = threadIdx.x & 31, ty = threadIdx.x >> 5;
#pragma unroll
  for (int i = 0; i < 32; i += 8)
    tile[ty + i][tx] = src[(size_t)(by + ty + i) * 1024 + bx + tx];
  __syncthreads();
#pragma unroll
  for (int i = 0; i < 32; i += 8)
    d[(size_t)(bx + ty + i) * 1024 + by + tx] = (__bf16)tile[tx][ty + i];
}

__global__ __launch_bounds__(256) void transpose_f2b_k(
    const float* __restrict__ src, __bf16* __restrict__ dst, int R, int C) {
  __shared__ float tile[32][33];
  const int bx = blockIdx.x * 32, by = blockIdx.y * 32;
  const int tx = threadIdx.x & 31, ty = threadIdx.x >> 5;
#pragma unroll
  for (int i = 0; i < 32; i += 8)
    tile[ty + i][tx] = src[(size_t)(by + ty + i) * C + bx + tx];
  __syncthreads();
#pragma unroll
  for (int i = 0; i < 32; i += 8)
    dst[(size_t)(bx + ty + i) * R + by + tx] = (__bf16)tile[tx][ty + i];
}

// batched bf16 transpose: per bh, [1024 s][64 d] -> [64 d][1024 s]
__global__ __launch_bounds__(256) void transpose_v_k(
    const __bf16* __restrict__ src, __bf16* __restrict__ dst) {
  __shared__ __bf16 tile[32][33];
  const int bh = blockIdx.z;
  const int s0 = blockIdx.x * 32, d0 = blockIdx.y * 32;
  const size_t base = (size_t)bh << 16;
  const int tx = threadIdx.x & 31, ty = threadIdx.x >> 5;
#pragma unroll
  for (int i = 0; i < 32; i += 8)
    tile[ty + i][tx] = src[base + (size_t)(s0 + ty + i) * 64 + d0 + tx];
  __syncthreads();
#pragma unroll
  for (int i = 0; i < 32; i += 8)
    dst[base + (size_t)(d0 + ty + i) * 1024 + s0 + tx] = tile[tx][ty + i];
}

__global__ __launch_bounds__(256) void convert_f2b_k(const float* __restrict__ s,
                                                     __bf16* __restrict__ d) {
  const size_t i = ((size_t)blockIdx.x * 256 + threadIdx.x) * 4;
  const float4 v = *(const float4*)(s + i);
  bf16x4 o;
  o[0] = (__bf16)v.x; o[1] = (__bf16)v.y; o[2] = (__bf16)v.z; o[3] = (__bf16)v.w;
  *(bf16x4*)(d + i) = o;
}

__global__ void concat3_k(const float* a, const float* b, const float* c,
                          float* o) {
  int i = blockIdx.x * 256 + threadIdx.x;
  if (i < 1024) o[i] = a[i];
  else if (i < 2048) o[i] = b[i - 1024];
  else if (i < 3072) o[i] = c[i - 2048];
}

// ---------------------------------------------------------------------------
// BK=32 staging: one gload stages 16 rows x 32 K (64 B/row) of a tile.
// LDS layout [row][32] with chunk swizzle: LDS[r][c16] = G[r][c16^((r>>1)&3)]
// (c16 = 16B chunk index 0..3). Dest linear (lane*16B: row=lane>>2,
// chunk=lane&3); source chunk = (lane&3)^((lane>>3)&3) since rows are
// 16-aligned. Fragment reads use chunk = quad^((l15>>1)&3) -> exactly
// uniform bank load (32 B/bank per b128 wave-op), conflict-free.
// ---------------------------------------------------------------------------
#define STG32(P, rowbase, Kld, kbase, DST)                                     \
  GLOBAL_LOAD_LDS16((P) + (size_t)((rowbase) + (lane >> 2)) * (Kld) +          \
                        (kbase) + s32,                                         \
                    (DST))

// ---------------------------------------------------------------------------
// gemm_t3: C[M,N] = A @ Bt^T + bias. BM={256,128}, BN=128, BK=32.
// 256 threads / 4 waves as 2M x 2N; wave tile (BM/2) x 64.
//   BM=256: 12 ds_read per 32 MFMA per wave (0.375 r/M, -25% LDS vs 64x64),
//           LDS 3x(256+128)x32x2B = 72 KiB -> 2 blocks/CU.
//   BM=128: 8 ds_read per 16 MFMA, LDS 48 KiB -> 2 blocks/CU (grid 512).
// Triple-buffered, 2-tile lookahead, COUNTED vmcnt(L) (L = loads/wave/tile):
// the wait covers loads issued a full iteration earlier (landed) -> no
// exposed HBM latency, unlike round-6's same-iteration vmcnt(0) drain.
// One barrier per K-tile. 2 co-resident blocks absorb residual stalls.
// Ledger: prologue stages t0,t1 (2L), vmcnt(L) -> t0 done. Iter t: stage
// t+2 (outstanding 2L), vmcnt(L) -> t+1 done. Never 0 in main loop.
// Supertile+XCD block map (round-8 verified: FETCH 139->65 MB).
// EPI: 0 plain, 1 ReLU, 2 QKV head-split scatter (N==3072)
// ---------------------------------------------------------------------------
template <int EPI, int BM>
__global__ __launch_bounds__(256, 2) void gemm_t3(const __bf16* __restrict__ A,
                                                  const __bf16* __restrict__ Bt,
                                                  const float* __restrict__ bias,
                                                  __bf16* __restrict__ C,
                                                  int M, int N, int K) {
  constexpr int F = BM / 32;        // A frags per wave (wave rows = BM/2)
  constexpr int LA = BM / 64;       // A gloads per wave per tile
  __shared__ __align__(16) __bf16 Abuf[3][BM * 32];
  __shared__ __align__(16) __bf16 Bbuf[3][128 * 32];
  const int tid = threadIdx.x;
  const int wave = tid >> 6, lane = tid & 63;
  const int quad = lane >> 4, l15 = lane & 15;
  const int wm = wave >> 1, wn = wave & 1;  // 2M x 2N

  // XCD swizzle + 8x8-tile supertile map (bijective: nwg%64==0, gy%8==0)
  const int nwg = gridDim.x;
  const int cpx = nwg >> 3;
  const int bid = blockIdx.x;
  const int wg = (bid & 7) * cpx + (bid >> 3);
  const int gy = N >> 7;
  const int nstc = gy >> 3;
  const int st = wg >> 6;
  const int r = wg & 63;
  const int stm = st / nstc, stn = st - stm * nstc;
  const int tm = (stm << 3) + (r >> 3);
  const int tn = (stn << 3) + (r & 7);
  const int m0 = tm * BM, n0 = tn << 7;

  const int s32 = (((lane & 3) ^ ((lane >> 3) & 3)) * 8);  // staging src chunk
  const int c0 = (quad ^ ((l15 >> 1) & 3)) * 8;            // frag read chunk
  const int aoff = (wm * (BM / 2) + l15) * 32;
  const int boff = (wn * 64 + l15) * 32;

  bf16x8 af[F], bfr[4];
  f32x4 acc[F][4] = {};

  const int NT = K >> 5;

  const __bf16* a_c = Abuf[0];
  const __bf16* a_n = Abuf[1];
  const __bf16* a_f = Abuf[2];
  const __bf16* b_c = Bbuf[0];
  const __bf16* b_n = Bbuf[1];
  const __bf16* b_f = Bbuf[2];

#define STAGE_TILE(kb, AD, BD)                                                 \
  do {                                                                         \
    _Pragma("unroll") for (int p_ = 0; p_ < LA; ++p_)                          \
        STG32(A, m0 + wave * (BM / 4) + p_ * 16, K, kb,                        \
              (__bf16*)(AD) + (wave * (BM / 4) + p_ * 16) * 32);               \
    _Pragma("unroll") for (int p_ = 0; p_ < 2; ++p_)                           \
        STG32(Bt, n0 + wave * 32 + p_ * 16, K, kb,                             \
              (__bf16*)(BD) + (wave * 32 + p_ * 16) * 32);                     \
  } while (0)

#define WAIT_L()                                                               \
  do {                                                                         \
    if constexpr (BM == 256)                                                   \
      asm volatile("s_waitcnt vmcnt(6)" ::: "memory");                         \
    else                                                                       \
      asm volatile("s_waitcnt vmcnt(4)" ::: "memory");                         \
  } while (0)

  // prologue: stage t0 and t1; wait t0 only, keep t1 in flight.
  STAGE_TILE(0, a_c, b_c);
  STAGE_TILE(32, a_n, b_n);
  WAIT_L();
  __builtin_amdgcn_s_barrier();
  asm volatile("" ::: "memory");

  for (int t = 0; t < NT; ++t) {
    // current-tile fragment reads (natural order; compiler counts lgkm)
#pragma unroll
    for (int f = 0; f < F; ++f)
      af[f] = *(const bf16x8*)(a_c + aoff + f * 512 + c0);
#pragma unroll
    for (int g = 0; g < 4; ++g)
      bfr[g] = *(const bf16x8*)(b_c + boff + g * 512 + c0);
    // stage tile t+2 into the far buffer
    const bool pf = (t + 2 < NT);
    if (pf) STAGE_TILE((t + 2) << 5, a_f, b_f);
    __builtin_amdgcn_s_setprio(1);
#pragma unroll
    for (int f = 0; f < F; ++f)
#pragma unroll
      for (int g = 0; g < 4; ++g)
        acc[f][g] = __builtin_amdgcn_mfma_f32_16x16x32_bf16(
            af[f], bfr[g], acc[f][g], 0, 0, 0);
    __builtin_amdgcn_s_setprio(0);
    // publish tile t+1: counted vmcnt (never 0 mid-loop), then barrier.
    if (pf) {
      WAIT_L();
      __builtin_amdgcn_s_barrier();
      asm volatile("" ::: "memory");
    } else if (t + 1 < NT) {
      asm volatile("s_waitcnt vmcnt(0)" ::: "memory");
      __builtin_amdgcn_s_barrier();
      asm volatile("" ::: "memory");
    }
    // rotate buffers
    const __bf16* ta = a_c; a_c = a_n; a_n = a_f; a_f = ta;
    const __bf16* tb = b_c; b_c = b_n; b_n = b_f; b_f = tb;
  }

  // epilogue: D layout col=l15, row=quad*4+i within each 16x16 frag
  float bvv[4];
#pragma unroll
  for (int g = 0; g < 4; ++g) bvv[g] = bias[n0 + wn * 64 + g * 16 + l15];
#pragma unroll
  for (int f = 0; f < F; ++f)
#pragma unroll
    for (int i = 0; i < 4; ++i) {
      const int row = m0 + wm * (BM / 2) + f * 16 + quad * 4 + i;
#pragma unroll
      for (int g = 0; g < 4; ++g) {
        const int col = n0 + wn * 64 + g * 16 + l15;
        float v = acc[f][g][i] + bvv[g];
        if (EPI == 1) v = fmaxf(v, 0.0f);
        size_t oidx;
        if (EPI == 2) {
          const int which = col >> 10, wi = col & 1023;
          const int h = wi >> 6, d = wi & 63;
          const int b = row >> 10, s = row & 1023;
          oidx = ((size_t)which << 23) +
                 (((size_t)(b * 16 + h) << 16) + s * 64 + d);
        } else {
          oidx = (size_t)row * N + col;
        }
        C[oidx] = (__bf16)v;
      }
    }
#undef STAGE_TILE
#undef WAIT_L
}

// ---------------------------------------------------------------------------
// Flash attention (round-7 measured config): causal strict, row 0 zeroed.
// ---------------------------------------------------------------------------
__global__ __launch_bounds__(256) void attn_kernel(const __bf16* __restrict__ Q,
                                                   const __bf16* __restrict__ Kg,
                                                   const __bf16* __restrict__ Vt,
                                                   __bf16* __restrict__ ctx) {
  const int qp = blockIdx.x;   // 0..3
  const int bh = blockIdx.y;   // 0..127
  const int b = bh >> 4, h = bh & 15;
  const int tid = threadIdx.x, wave = tid >> 6, lane = tid & 63;
  const int quad = lane >> 4, l15 = lane & 15;
  const size_t hoff = (size_t)bh << 16;
  const __bf16* Qh = Q + hoff;
  const __bf16* Kh = Kg + hoff;
  const __bf16* Vh = Vt + hoff;

  __shared__ __align__(16) __bf16 Ks[64 * 64];
  __shared__ __align__(16) __bf16 Vs[64 * 64];
  __shared__ __align__(16) __bf16 Ps[4][32 * 72];
  __shared__ float lL[128];

  const int skey = wave * 8 + (lane >> 3);
  const int sgr = lane & 7;

#pragma unroll
  for (int pass = 0; pass < 2; ++pass) {
    const int qt = pass ? (7 - qp) : qp;
    const int qb = qt * 128;

    bf16x8 qf[2][2];
#pragma unroll
    for (int g = 0; g < 2; ++g) {
      const int qrow = qb + wave * 32 + g * 16 + l15;
      bf16x8 t0 = *(const bf16x8*)(Qh + (size_t)qrow * 64 + quad * 8);
      bf16x8 t1 = *(const bf16x8*)(Qh + (size_t)qrow * 64 + 32 + quad * 8);
#pragma unroll
      for (int e = 0; e < 8; ++e) {
        qf[g][0][e] = (__bf16)((float)t0[e] * 0.125f);
        qf[g][1][e] = (__bf16)((float)t1[e] * 0.125f);
      }
    }

    f32x4 oacc[4][2] = {};
    float lrun[2][4] = {};

    const int ktmax = 2 * qt + 1;
    for (int kt = 0; kt <= ktmax; ++kt) {
      __syncthreads();
#pragma unroll
      for (int j = 0; j < 2; ++j) {
        const int row = skey + 32 * j;
        GLOBAL_LOAD_LDS16(
            Kh + (size_t)(kt * 64 + row) * 64 + ((sgr ^ (row & 7)) * 8),
            Ks + j * 2048 + wave * 512);
        GLOBAL_LOAD_LDS16(
            Vh + (size_t)row * 1024 + kt * 64 + ((sgr ^ (row & 7)) * 8),
            Vs + j * 2048 + wave * 512);
      }
      __syncthreads();

      f32x4 sacc[2][4] = {};
#pragma unroll
      for (int nt = 0; nt < 4; ++nt) {
        const int key = nt * 16 + l15, sw = key & 7;
        bf16x8 kf0 = *(const bf16x8*)(Ks + key * 64 + ((quad ^ sw) * 8));
        bf16x8 kf1 = *(const bf16x8*)(Ks + key * 64 + (((quad + 4) ^ sw) * 8));
#pragma unroll
        for (int g = 0; g < 2; ++g) {
          sacc[g][nt] = __builtin_amdgcn_mfma_f32_16x16x32_bf16(
              qf[g][0], kf0, sacc[g][nt], 0, 0, 0);
          sacc[g][nt] = __builtin_amdgcn_mfma_f32_16x16x32_bf16(
              qf[g][1], kf1, sacc[g][nt], 0, 0, 0);
        }
      }

      const bool tilemask = (kt >= 2 * qt);
#pragma unroll
      for (int g = 0; g < 2; ++g)
#pragma unroll
        for (int nt = 0; nt < 4; ++nt) {
          const int key = kt * 64 + nt * 16 + l15;
#pragma unroll
          for (int r = 0; r < 4; ++r) {
            float p = __expf(fminf(sacc[g][nt][r], 60.0f));
            if (tilemask && key >= qb + wave * 32 + g * 16 + quad * 4 + r)
              p = 0.0f;
            sacc[g][nt][r] = p;
            lrun[g][r] += p;
          }
        }

#pragma unroll
      for (int g = 0; g < 2; ++g)
#pragma unroll
        for (int nt = 0; nt < 4; ++nt)
#pragma unroll
          for (int r = 0; r < 4; ++r)
            Ps[wave][(g * 16 + quad * 4 + r) * 72 + nt * 16 + l15] =
                (__bf16)sacc[g][nt][r];

#pragma unroll
      for (int kc = 0; kc < 2; ++kc) {
        bf16x8 pf[2];
#pragma unroll
        for (int g = 0; g < 2; ++g)
          pf[g] = *(const bf16x8*)(&Ps[wave][(g * 16 + l15) * 72 + kc * 32 +
                                             quad * 8]);
#pragma unroll
        for (int mdt = 0; mdt < 4; ++mdt) {
          const int d = mdt * 16 + l15, sw = d & 7;
          bf16x8 vf =
              *(const bf16x8*)(Vs + d * 64 + (((kc * 4 + quad) ^ sw) * 8));
#pragma unroll
          for (int g = 0; g < 2; ++g)
            oacc[mdt][g] = __builtin_amdgcn_mfma_f32_16x16x32_bf16(
                vf, pf[g], oacc[mdt][g], 0, 0, 0);
        }
      }
    }

#pragma unroll
    for (int g = 0; g < 2; ++g)
#pragma unroll
      for (int r = 0; r < 4; ++r) {
        float s = lrun[g][r];
#pragma unroll
        for (int d = 1; d < 16; d <<= 1) s += __shfl_xor(s, d);
        if (l15 == 0) lL[wave * 32 + g * 16 + quad * 4 + r] = s;
      }
    float linv[2];
#pragma unroll
    for (int g = 0; g < 2; ++g) {
      const float l = lL[wave * 32 + g * 16 + l15];
      linv[g] = (qb + wave * 32 + g * 16 + l15 == 0) ? 0.0f : (1.0f / l);
    }
    __bf16* Ot = Ps[wave];
#pragma unroll
    for (int mdt = 0; mdt < 4; ++mdt)
#pragma unroll
      for (int g = 0; g < 2; ++g)
#pragma unroll
        for (int r = 0; r < 4; ++r)
          Ot[(g * 16 + l15) * 72 + mdt * 16 + quad * 4 + r] =
              (__bf16)(oacc[mdt][g][r] * linv[g]);
#pragma unroll
    for (int rr = 0; rr < 2; ++rr)
#pragma unroll
      for (int j = 0; j < 2; ++j) {
        const int row = rr * 16 + (lane >> 2), chk = (lane & 3) + 4 * j;
        bf16x8 ov = *(const bf16x8*)(Ot + row * 72 + chk * 8);
        const size_t oi = ((size_t)(b * 1024 + qb + wave * 32 + row)) * 1024 +
                          h * 64 + chk * 8;
        *(bf16x8*)(ctx + oi) = ov;
      }
  }
}

// ---------------------------------------------------------------------------
// out = LayerNorm(x + y) * g + beta ; rows of 1024, one block per row.
// ---------------------------------------------------------------------------
template <typename TX, typename TY, typename TO>
__global__ __launch_bounds__(256) void add_ln_kernel(const TX* __restrict__ x,
                                                     const TY* __restrict__ y,
                                                     const float* __restrict__ g,
                                                     const float* __restrict__ be,
                                                     TO* __restrict__ out) {
  const int row = blockIdx.x;
  const size_t base = (size_t)row * 1024;
  const int t = threadIdx.x;
  float xv[4], yv[4];
  if constexpr (sizeof(TX) == 4) {
    const float4 a = *(const float4*)(x + base + t * 4);
    xv[0] = a.x; xv[1] = a.y; xv[2] = a.z; xv[3] = a.w;
  } else {
    const bf16x4 a = *(const bf16x4*)(x + base + t * 4);
#pragma unroll
    for (int i = 0; i < 4; ++i) xv[i] = (float)a[i];
  }
  if constexpr (sizeof(TY) == 4) {
    const float4 a = *(const float4*)(y + base + t * 4);
    yv[0] = a.x; yv[1] = a.y; yv[2] = a.z; yv[3] = a.w;
  } else {
    const bf16x4 a = *(const bf16x4*)(y + base + t * 4);
#pragma unroll
    for (int i = 0; i < 4; ++i) yv[i] = (float)a[i];
  }
  float v[4], s = 0.0f, s2 = 0.0f;
#pragma unroll
  for (int i = 0; i < 4; ++i) {
    v[i] = xv[i] + yv[i];
    s += v[i];
    s2 += v[i] * v[i];
  }
#pragma unroll
  for (int m = 1; m < 64; m <<= 1) {
    s += __shfl_xor(s, m);
    s2 += __shfl_xor(s2, m);
  }
  __shared__ float ss[4], ss2[4];
  const int w = t >> 6;
  if ((t & 63) == 0) { ss[w] = s; ss2[w] = s2; }
  __syncthreads();
  s = ss[0] + ss[1] + ss[2] + ss[3];
  s2 = ss2[0] + ss2[1] + ss2[2] + ss2[3];
  const float mu = s * (1.0f / 1024.0f);
  const float var = s2 * (1.0f / 1024.0f) - mu * mu;
  const float rstd = rsqrtf(var + 1e-5f);
#pragma unroll
  for (int i = 0; i < 4; ++i) {
    const float o = (v[i] - mu) * rstd * g[t * 4 + i] + be[t * 4 + i];
    out[base + t * 4 + i] = (TO)o;
  }
}

// ---------------------------------------------------------------------------
extern "C" void kernel_launch(void* const* d_in, const int* in_sizes, int n_in,
                              void* d_out, int out_size, void* d_ws,
                              size_t ws_size, hipStream_t stream) {
  (void)in_sizes; (void)n_in; (void)out_size; (void)ws_size;
  const float* x   = (const float*)d_in[0];
  const float* Wq  = (const float*)d_in[1];
  const float* bq  = (const float*)d_in[2];
  const float* Wk  = (const float*)d_in[3];
  const float* bk  = (const float*)d_in[4];
  const float* Wv  = (const float*)d_in[5];
  const float* bv  = (const float*)d_in[6];
  const float* Wo  = (const float*)d_in[7];
  const float* bo  = (const float*)d_in[8];
  const float* W1  = (const float*)d_in[9];
  const float* b1  = (const float*)d_in[10];
  const float* W2  = (const float*)d_in[11];
  const float* b2  = (const float*)d_in[12];
  const float* g1  = (const float*)d_in[13];
  const float* be1 = (const float*)d_in[14];
  const float* g3  = (const float*)d_in[15];
  const float* be3 = (const float*)d_in[16];

  char* ws = (char*)d_ws;
  __bf16* Qb    = (__bf16*)(ws + 0);
  __bf16* Kb    = (__bf16*)(ws + (16u << 20));
  __bf16* Vb    = (__bf16*)(ws + (32u << 20));
  __bf16* ctx   = (__bf16*)(ws + (48u << 20));
  __bf16* mid   = (__bf16*)(ws + 0);
  __bf16* aout  = (__bf16*)(ws + (64u << 20));
  __bf16* h1    = aout;
  __bf16* xb    = (__bf16*)(ws + (80u << 20));
  __bf16* Vtb   = (__bf16*)(ws + (80u << 20));
  __bf16* fout  = (__bf16*)(ws + (80u << 20));
  __bf16* WqkvT = (__bf16*)(ws + (96u << 20));
  __bf16* WoT   = (__bf16*)(ws + (96u << 20) + 3 * (1u << 21));
  __bf16* W1T   = (__bf16*)(ws + (104u << 20));
  __bf16* W2T   = (__bf16*)(ws + (112u << 20));
  float*  bqkv  = (float*)(ws + (120u << 20));
  float*  outp  = (float*)d_out;

  const dim3 blk(256);
  // ---- prep
  convert_f2b_k<<<dim3(8192), blk, 0, stream>>>(x, xb);
  transpose4_f2b_k<<<dim3(32, 32, 4), blk, 0, stream>>>(Wq, Wk, Wv, Wo, WqkvT);
  transpose_f2b_k<<<dim3(128, 32), blk, 0, stream>>>(W1, W1T, 1024, 4096);
  transpose_f2b_k<<<dim3(32, 128), blk, 0, stream>>>(W2, W2T, 4096, 1024);
  concat3_k<<<dim3(12), blk, 0, stream>>>(bq, bk, bv, bqkv);

  // ---- QKV fused projection (head-split scatter), 768 blocks, BM=256
  gemm_t3<2, 256><<<dim3(768), blk, 0, stream>>>(xb, WqkvT, bqkv, Qb,
                                                 8192, 3072, 1024);
  // ---- V -> V^T per (b,h)
  transpose_v_k<<<dim3(32, 2, 128), blk, 0, stream>>>(Vb, Vtb);
  // ---- attention
  attn_kernel<<<dim3(4, 128), blk, 0, stream>>>(Qb, Kb, Vtb, ctx);
  // ---- output projection, 512 blocks, BM=128
  gemm_t3<0, 128><<<dim3(512), blk, 0, stream>>>(ctx, WoT, bo, aout,
                                                 8192, 1024, 1024);
  // ---- h1 = LN(x + attn_out)
  add_ln_kernel<float, __bf16, __bf16><<<dim3(8192), blk, 0, stream>>>(
      x, aout, g1, be1, h1);
  // ---- FFN
  gemm_t3<1, 256><<<dim3(1024), blk, 0, stream>>>(h1, W1T, b1, mid,
                                                  8192, 4096, 1024);
  gemm_t3<0, 128><<<dim3(512), blk, 0, stream>>>(mid, W2T, b2, fout,
                                                 8192, 1024, 4096);
  // ---- out = LN(h1 + ffn)
  add_ln_kernel<__bf16, __bf16, float><<<dim3(8192), blk, 0, stream>>>(
      h1, fout, g3, be3, outp);
}

// Round 10
// 472.661 us; speedup vs baseline: 1.0276x; 1.0276x over previous
//
#include <hip/hip_runtime.h>
#include <hip/hip_bf16.h>

typedef __bf16 bf16x8 __attribute__((ext_vector_type(8)));
typedef __bf16 bf16x4 __attribute__((ext_vector_type(4)));
typedef float f32x4 __attribute__((ext_vector_type(4)));

#define GLOBAL_LOAD_LDS16(gp, lp)                                              \
  __builtin_amdgcn_global_load_lds(                                            \
      (const __attribute__((address_space(1))) void*)(gp),                     \
      (__attribute__((address_space(3))) void*)(lp), 16, 0, 0)

// ---------------------------------------------------------------------------
// Prep kernels (one-time, bandwidth-bound)
// ---------------------------------------------------------------------------
__global__ __launch_bounds__(256) void transpose4_f2b_k(
    const float* __restrict__ s0, const float* __restrict__ s1,
    const float* __restrict__ s2, const float* __restrict__ s3,
    __bf16* __restrict__ dst) {
  __shared__ float tile[32][33];
  const float* srcs[4] = {s0, s1, s2, s3};
  const float* src = srcs[blockIdx.z];
  __bf16* d = dst + ((size_t)blockIdx.z << 20);
  const int bx = blockIdx.x * 32, by = blockIdx.y * 32;
  const int tx = threadIdx.x & 31, ty = threadIdx.x >> 5;
#pragma unroll
  for (int i = 0; i < 32; i += 8)
    tile[ty + i][tx] = src[(size_t)(by + ty + i) * 1024 + bx + tx];
  __syncthreads();
#pragma unroll
  for (int i = 0; i < 32; i += 8)
    d[(size_t)(bx + ty + i) * 1024 + by + tx] = (__bf16)tile[tx][ty + i];
}

__global__ __launch_bounds__(256) void transpose_f2b_k(
    const float* __restrict__ src, __bf16* __restrict__ dst, int R, int C) {
  __shared__ float tile[32][33];
  const int bx = blockIdx.x * 32, by = blockIdx.y * 32;
  const int tx = threadIdx.x & 31, ty = threadIdx.x >> 5;
#pragma unroll
  for (int i = 0; i < 32; i += 8)
    tile[ty + i][tx] = src[(size_t)(by + ty + i) * C + bx + tx];
  __syncthreads();
#pragma unroll
  for (int i = 0; i < 32; i += 8)
    dst[(size_t)(bx + ty + i) * R + by + tx] = (__bf16)tile[tx][ty + i];
}

// batched bf16 transpose: per bh, [1024 s][64 d] -> [64 d][1024 s]
__global__ __launch_bounds__(256) void transpose_v_k(
    const __bf16* __restrict__ src, __bf16* __restrict__ dst) {
  __shared__ __bf16 tile[32][33];
  const int bh = blockIdx.z;
  const int s0 = blockIdx.x * 32, d0 = blockIdx.y * 32;
  const size_t base = (size_t)bh << 16;
  const int tx = threadIdx.x & 31, ty = threadIdx.x >> 5;
#pragma unroll
  for (int i = 0; i < 32; i += 8)
    tile[ty + i][tx] = src[base + (size_t)(s0 + ty + i) * 64 + d0 + tx];
  __syncthreads();
#pragma unroll
  for (int i = 0; i < 32; i += 8)
    dst[base + (size_t)(d0 + ty + i) * 1024 + s0 + tx] = tile[tx][ty + i];
}

__global__ __launch_bounds__(256) void convert_f2b_k(const float* __restrict__ s,
                                                     __bf16* __restrict__ d) {
  const size_t i = ((size_t)blockIdx.x * 256 + threadIdx.x) * 4;
  const float4 v = *(const float4*)(s + i);
  bf16x4 o;
  o[0] = (__bf16)v.x; o[1] = (__bf16)v.y; o[2] = (__bf16)v.z; o[3] = (__bf16)v.w;
  *(bf16x4*)(d + i) = o;
}

__global__ void concat3_k(const float* a, const float* b, const float* c,
                          float* o) {
  int i = blockIdx.x * 256 + threadIdx.x;
  if (i < 1024) o[i] = a[i];
  else if (i < 2048) o[i] = b[i - 1024];
  else if (i < 3072) o[i] = c[i - 2048];
}

// ---------------------------------------------------------------------------
// Staging macro: one wave stages 16 rows (2x8) of a [64.. x 64] bf16 region,
// linear LDS dest, pre-swizzled global source chunk (c ^= r&7).
// ---------------------------------------------------------------------------
#define STG(P, rowbase, Kld, kbase, DST)                                       \
  do {                                                                         \
    GLOBAL_LOAD_LDS16((P) + (size_t)((rowbase) + wave * 16 + srow) * (Kld) +   \
                          (kbase) + sch8,                                      \
                      (DST) + wave * 1024);                                    \
    GLOBAL_LOAD_LDS16((P) + (size_t)((rowbase) + wave * 16 + 8 + srow) *       \
                              (Kld) + (kbase) + sch8,                          \
                      (DST) + wave * 1024 + 512);                              \
  } while (0)

// ---------------------------------------------------------------------------
// gemm_db: C[M,N] = A @ Bt^T + bias. BM=BN=128, BK=64.  (round-8 verified
// best: FFN1 78.7us / 873 TF, FETCH 139->65 MB via supertile.)
// 256 threads / 4 waves as 2M x 2N (wave tile 64x64). DOUBLE-buffered LDS
// (64 KiB total -> 2 blocks/CU, 16 waves/CU), 1-K-tile prefetch lookahead,
// one barrier per K-tile. Round-10 change: STAGE-FIRST ordering (round-3's
// verified-safe order) — the 8 global_load_lds for t+1 issue BEFORE the 16
// ds_reads, so their flight covers ds-read issue + MFMA window, shrinking
// the exposed vmcnt(0) drain at iteration end.
//   [8 global_load_lds (t+1 -> buf nxt) | 16 ds_read (buf cur) | setprio1 |
//    32 MFMA | setprio0 | vmcnt(0) | s_barrier | swap]
// Buffer safety: staging buf[nxt] in iter t occurs after barrier(t-1); all
// waves' reads of buf[nxt] (iter t-1) were lgkm-drained by their MFMAs
// before reaching barrier(t-1).
// EPI: 0 plain, 1 ReLU, 2 QKV head-split scatter (N==3072)
// ---------------------------------------------------------------------------
template <int EPI>
__global__ __launch_bounds__(256, 2) void gemm_db(const __bf16* __restrict__ A,
                                                  const __bf16* __restrict__ Bt,
                                                  const float* __restrict__ bias,
                                                  __bf16* __restrict__ C,
                                                  int M, int N, int K) {
  __shared__ __align__(16) __bf16 Abuf[2][128 * 64];  // 32 KiB
  __shared__ __align__(16) __bf16 Bbuf[2][128 * 64];  // 32 KiB
  const int tid = threadIdx.x;
  const int wave = tid >> 6, lane = tid & 63;
  const int quad = lane >> 4, l15 = lane & 15;
  const int wm = wave >> 1, wn = wave & 1;  // 2M x 2N

  // XCD-aware bijective swizzle (nwg % 8 == 0 for all launches), then
  // 8x8-tile supertile mapping within each XCD's contiguous wg range.
  const int nwg = gridDim.x;
  const int cpx = nwg >> 3;
  const int bid = blockIdx.x;
  const int wg = (bid & 7) * cpx + (bid >> 3);
  const int gy = N >> 7;
  const int nstc = gy >> 3;              // supertile columns
  const int st = wg >> 6;                // supertile index (row-major)
  const int r = wg & 63;                 // block within supertile
  const int stm = st / nstc, stn = st - stm * nstc;
  const int tm = (stm << 3) + (r >> 3);
  const int tn = (stn << 3) + (r & 7);
  const int m0 = tm << 7, n0 = tn << 7;

  const int srow = lane >> 3;
  const int sch8 = ((lane & 7) ^ srow) * 8;      // pre-swizzled source chunk
  const int aoff = (wm * 64 + l15) * 64;         // A row base in [128][64]
  const int boff = (wn * 64 + l15) * 64;         // B row base in [128][64]
  const int c0 = (quad ^ (l15 & 7)) * 8;         // swizzled k-chunk (kh=0)

  bf16x8 af[4][2], bfr[4][2];
  f32x4 acc[4][4] = {};  // [f (A frag)][g (B frag)]

  const int NT = K >> 6;

  const __bf16* a_c = Abuf[0];
  const __bf16* a_n = Abuf[1];
  const __bf16* b_c = Bbuf[0];
  const __bf16* b_n = Bbuf[1];

  // prologue: stage tile 0 into buf0 (8 loads/wave-group), drain, publish.
  STG(A, m0, K, 0, (__bf16*)a_c);
  STG(A, m0 + 64, K, 0, (__bf16*)a_c + 64 * 64);
  STG(Bt, n0, K, 0, (__bf16*)b_c);
  STG(Bt, n0 + 64, K, 0, (__bf16*)b_c + 64 * 64);
  asm volatile("s_waitcnt vmcnt(0)" ::: "memory");
  __builtin_amdgcn_s_barrier();
  asm volatile("" ::: "memory");

  for (int t = 0; t < NT; ++t) {
    // stage tile t+1 FIRST (max flight time before the end-of-iter drain)
    const int kn = (t + 1) << 6;
    const bool pf = (t + 1 < NT);
    if (pf) {
      STG(A, m0, K, kn, (__bf16*)a_n);
      STG(A, m0 + 64, K, kn, (__bf16*)a_n + 64 * 64);
      STG(Bt, n0, K, kn, (__bf16*)b_n);
      STG(Bt, n0 + 64, K, kn, (__bf16*)b_n + 64 * 64);
    }
    // current-tile fragment reads (natural order; compiler schedules lgkm)
#pragma unroll
    for (int f = 0; f < 4; ++f) {
      af[f][0] = *(const bf16x8*)(a_c + aoff + f * 1024 + c0);
      af[f][1] = *(const bf16x8*)(a_c + aoff + f * 1024 + (c0 ^ 32));
    }
#pragma unroll
    for (int g = 0; g < 4; ++g) {
      bfr[g][0] = *(const bf16x8*)(b_c + boff + g * 1024 + c0);
      bfr[g][1] = *(const bf16x8*)(b_c + boff + g * 1024 + (c0 ^ 32));
    }
    __builtin_amdgcn_s_setprio(1);
#pragma unroll
    for (int f = 0; f < 4; ++f)
#pragma unroll
      for (int g = 0; g < 4; ++g) {
        acc[f][g] = __builtin_amdgcn_mfma_f32_16x16x32_bf16(
            af[f][0], bfr[g][0], acc[f][g], 0, 0, 0);
        acc[f][g] = __builtin_amdgcn_mfma_f32_16x16x32_bf16(
            af[f][1], bfr[g][1], acc[f][g], 0, 0, 0);
      }
    __builtin_amdgcn_s_setprio(0);
    if (pf) {
      asm volatile("s_waitcnt vmcnt(0)" ::: "memory");
      __builtin_amdgcn_s_barrier();
      asm volatile("" ::: "memory");
    }
    // swap buffers
    const __bf16* ta = a_c; a_c = a_n; a_n = ta;
    const __bf16* tb = b_c; b_c = b_n; b_n = tb;
  }

  // epilogue: D layout col=l15, row=quad*4+i within each 16x16 frag
  float bvv[4];
#pragma unroll
  for (int g = 0; g < 4; ++g) bvv[g] = bias[n0 + wn * 64 + g * 16 + l15];
#pragma unroll
  for (int f = 0; f < 4; ++f)
#pragma unroll
    for (int i = 0; i < 4; ++i) {
      const int row = m0 + wm * 64 + f * 16 + quad * 4 + i;
#pragma unroll
      for (int g = 0; g < 4; ++g) {
        const int col = n0 + wn * 64 + g * 16 + l15;
        float v = acc[f][g][i] + bvv[g];
        if (EPI == 1) v = fmaxf(v, 0.0f);
        size_t oidx;
        if (EPI == 2) {
          const int which = col >> 10, wi = col & 1023;
          const int h = wi >> 6, d = wi & 63;
          const int b = row >> 10, s = row & 1023;
          oidx = ((size_t)which << 23) +
                 (((size_t)(b * 16 + h) << 16) + s * 64 + d);
        } else {
          oidx = (size_t)row * N + col;
        }
        C[oidx] = (__bf16)v;
      }
    }
}

// ---------------------------------------------------------------------------
// Flash attention: causal strict, row 0 zeroed. Round-10: setprio (T5, m191)
// around QK^T and PV MFMA clusters.
// ---------------------------------------------------------------------------
__global__ __launch_bounds__(256) void attn_kernel(const __bf16* __restrict__ Q,
                                                   const __bf16* __restrict__ Kg,
                                                   const __bf16* __restrict__ Vt,
                                                   __bf16* __restrict__ ctx) {
  const int qp = blockIdx.x;   // 0..3
  const int bh = blockIdx.y;   // 0..127
  const int b = bh >> 4, h = bh & 15;
  const int tid = threadIdx.x, wave = tid >> 6, lane = tid & 63;
  const int quad = lane >> 4, l15 = lane & 15;
  const size_t hoff = (size_t)bh << 16;
  const __bf16* Qh = Q + hoff;
  const __bf16* Kh = Kg + hoff;
  const __bf16* Vh = Vt + hoff;

  __shared__ __align__(16) __bf16 Ks[64 * 64];
  __shared__ __align__(16) __bf16 Vs[64 * 64];
  __shared__ __align__(16) __bf16 Ps[4][32 * 72];
  __shared__ float lL[128];

  const int skey = wave * 8 + (lane >> 3);
  const int sgr = lane & 7;

#pragma unroll
  for (int pass = 0; pass < 2; ++pass) {
    const int qt = pass ? (7 - qp) : qp;
    const int qb = qt * 128;

    bf16x8 qf[2][2];
#pragma unroll
    for (int g = 0; g < 2; ++g) {
      const int qrow = qb + wave * 32 + g * 16 + l15;
      bf16x8 t0 = *(const bf16x8*)(Qh + (size_t)qrow * 64 + quad * 8);
      bf16x8 t1 = *(const bf16x8*)(Qh + (size_t)qrow * 64 + 32 + quad * 8);
#pragma unroll
      for (int e = 0; e < 8; ++e) {
        qf[g][0][e] = (__bf16)((float)t0[e] * 0.125f);
        qf[g][1][e] = (__bf16)((float)t1[e] * 0.125f);
      }
    }

    f32x4 oacc[4][2] = {};
    float lrun[2][4] = {};

    const int ktmax = 2 * qt + 1;
    for (int kt = 0; kt <= ktmax; ++kt) {
      __syncthreads();
#pragma unroll
      for (int j = 0; j < 2; ++j) {
        const int row = skey + 32 * j;
        GLOBAL_LOAD_LDS16(
            Kh + (size_t)(kt * 64 + row) * 64 + ((sgr ^ (row & 7)) * 8),
            Ks + j * 2048 + wave * 512);
        GLOBAL_LOAD_LDS16(
            Vh + (size_t)row * 1024 + kt * 64 + ((sgr ^ (row & 7)) * 8),
            Vs + j * 2048 + wave * 512);
      }
      __syncthreads();

      f32x4 sacc[2][4] = {};
      __builtin_amdgcn_s_setprio(1);
#pragma unroll
      for (int nt = 0; nt < 4; ++nt) {
        const int key = nt * 16 + l15, sw = key & 7;
        bf16x8 kf0 = *(const bf16x8*)(Ks + key * 64 + ((quad ^ sw) * 8));
        bf16x8 kf1 = *(const bf16x8*)(Ks + key * 64 + (((quad + 4) ^ sw) * 8));
#pragma unroll
        for (int g = 0; g < 2; ++g) {
          sacc[g][nt] = __builtin_amdgcn_mfma_f32_16x16x32_bf16(
              qf[g][0], kf0, sacc[g][nt], 0, 0, 0);
          sacc[g][nt] = __builtin_amdgcn_mfma_f32_16x16x32_bf16(
              qf[g][1], kf1, sacc[g][nt], 0, 0, 0);
        }
      }
      __builtin_amdgcn_s_setprio(0);

      const bool tilemask = (kt >= 2 * qt);
#pragma unroll
      for (int g = 0; g < 2; ++g)
#pragma unroll
        for (int nt = 0; nt < 4; ++nt) {
          const int key = kt * 64 + nt * 16 + l15;
#pragma unroll
          for (int r = 0; r < 4; ++r) {
            float p = __expf(fminf(sacc[g][nt][r], 60.0f));
            if (tilemask && key >= qb + wave * 32 + g * 16 + quad * 4 + r)
              p = 0.0f;
            sacc[g][nt][r] = p;
            lrun[g][r] += p;
          }
        }

#pragma unroll
      for (int g = 0; g < 2; ++g)
#pragma unroll
        for (int nt = 0; nt < 4; ++nt)
#pragma unroll
          for (int r = 0; r < 4; ++r)
            Ps[wave][(g * 16 + quad * 4 + r) * 72 + nt * 16 + l15] =
                (__bf16)sacc[g][nt][r];

#pragma unroll
      for (int kc = 0; kc < 2; ++kc) {
        bf16x8 pf[2];
#pragma unroll
        for (int g = 0; g < 2; ++g)
          pf[g] = *(const bf16x8*)(&Ps[wave][(g * 16 + l15) * 72 + kc * 32 +
                                             quad * 8]);
        __builtin_amdgcn_s_setprio(1);
#pragma unroll
        for (int mdt = 0; mdt < 4; ++mdt) {
          const int d = mdt * 16 + l15, sw = d & 7;
          bf16x8 vf =
              *(const bf16x8*)(Vs + d * 64 + (((kc * 4 + quad) ^ sw) * 8));
#pragma unroll
          for (int g = 0; g < 2; ++g)
            oacc[mdt][g] = __builtin_amdgcn_mfma_f32_16x16x32_bf16(
                vf, pf[g], oacc[mdt][g], 0, 0, 0);
        }
        __builtin_amdgcn_s_setprio(0);
      }
    }

#pragma unroll
    for (int g = 0; g < 2; ++g)
#pragma unroll
      for (int r = 0; r < 4; ++r) {
        float s = lrun[g][r];
#pragma unroll
        for (int d = 1; d < 16; d <<= 1) s += __shfl_xor(s, d);
        if (l15 == 0) lL[wave * 32 + g * 16 + quad * 4 + r] = s;
      }
    float linv[2];
#pragma unroll
    for (int g = 0; g < 2; ++g) {
      const float l = lL[wave * 32 + g * 16 + l15];
      linv[g] = (qb + wave * 32 + g * 16 + l15 == 0) ? 0.0f : (1.0f / l);
    }
    __bf16* Ot = Ps[wave];
#pragma unroll
    for (int mdt = 0; mdt < 4; ++mdt)
#pragma unroll
      for (int g = 0; g < 2; ++g)
#pragma unroll
        for (int r = 0; r < 4; ++r)
          Ot[(g * 16 + l15) * 72 + mdt * 16 + quad * 4 + r] =
              (__bf16)(oacc[mdt][g][r] * linv[g]);
#pragma unroll
    for (int rr = 0; rr < 2; ++rr)
#pragma unroll
      for (int j = 0; j < 2; ++j) {
        const int row = rr * 16 + (lane >> 2), chk = (lane & 3) + 4 * j;
        bf16x8 ov = *(const bf16x8*)(Ot + row * 72 + chk * 8);
        const size_t oi = ((size_t)(b * 1024 + qb + wave * 32 + row)) * 1024 +
                          h * 64 + chk * 8;
        *(bf16x8*)(ctx + oi) = ov;
      }
  }
}

// ---------------------------------------------------------------------------
// out = LayerNorm(x + y) * g + beta ; rows of 1024, one block per row.
// ---------------------------------------------------------------------------
template <typename TX, typename TY, typename TO>
__global__ __launch_bounds__(256) void add_ln_kernel(const TX* __restrict__ x,
                                                     const TY* __restrict__ y,
                                                     const float* __restrict__ g,
                                                     const float* __restrict__ be,
                                                     TO* __restrict__ out) {
  const int row = blockIdx.x;
  const size_t base = (size_t)row * 1024;
  const int t = threadIdx.x;
  float xv[4], yv[4];
  if constexpr (sizeof(TX) == 4) {
    const float4 a = *(const float4*)(x + base + t * 4);
    xv[0] = a.x; xv[1] = a.y; xv[2] = a.z; xv[3] = a.w;
  } else {
    const bf16x4 a = *(const bf16x4*)(x + base + t * 4);
#pragma unroll
    for (int i = 0; i < 4; ++i) xv[i] = (float)a[i];
  }
  if constexpr (sizeof(TY) == 4) {
    const float4 a = *(const float4*)(y + base + t * 4);
    yv[0] = a.x; yv[1] = a.y; yv[2] = a.z; yv[3] = a.w;
  } else {
    const bf16x4 a = *(const bf16x4*)(y + base + t * 4);
#pragma unroll
    for (int i = 0; i < 4; ++i) yv[i] = (float)a[i];
  }
  float v[4], s = 0.0f, s2 = 0.0f;
#pragma unroll
  for (int i = 0; i < 4; ++i) {
    v[i] = xv[i] + yv[i];
    s += v[i];
    s2 += v[i] * v[i];
  }
#pragma unroll
  for (int m = 1; m < 64; m <<= 1) {
    s += __shfl_xor(s, m);
    s2 += __shfl_xor(s2, m);
  }
  __shared__ float ss[4], ss2[4];
  const int w = t >> 6;
  if ((t & 63) == 0) { ss[w] = s; ss2[w] = s2; }
  __syncthreads();
  s = ss[0] + ss[1] + ss[2] + ss[3];
  s2 = ss2[0] + ss2[1] + ss2[2] + ss2[3];
  const float mu = s * (1.0f / 1024.0f);
  const float var = s2 * (1.0f / 1024.0f) - mu * mu;
  const float rstd = rsqrtf(var + 1e-5f);
#pragma unroll
  for (int i = 0; i < 4; ++i) {
    const float o = (v[i] - mu) * rstd * g[t * 4 + i] + be[t * 4 + i];
    out[base + t * 4 + i] = (TO)o;
  }
}

// ---------------------------------------------------------------------------
extern "C" void kernel_launch(void* const* d_in, const int* in_sizes, int n_in,
                              void* d_out, int out_size, void* d_ws,
                              size_t ws_size, hipStream_t stream) {
  (void)in_sizes; (void)n_in; (void)out_size; (void)ws_size;
  const float* x   = (const float*)d_in[0];
  const float* Wq  = (const float*)d_in[1];
  const float* bq  = (const float*)d_in[2];
  const float* Wk  = (const float*)d_in[3];
  const float* bk  = (const float*)d_in[4];
  const float* Wv  = (const float*)d_in[5];
  const float* bv  = (const float*)d_in[6];
  const float* Wo  = (const float*)d_in[7];
  const float* bo  = (const float*)d_in[8];
  const float* W1  = (const float*)d_in[9];
  const float* b1  = (const float*)d_in[10];
  const float* W2  = (const float*)d_in[11];
  const float* b2  = (const float*)d_in[12];
  const float* g1  = (const float*)d_in[13];
  const float* be1 = (const float*)d_in[14];
  const float* g3  = (const float*)d_in[15];
  const float* be3 = (const float*)d_in[16];

  char* ws = (char*)d_ws;
  __bf16* Qb    = (__bf16*)(ws + 0);
  __bf16* Kb    = (__bf16*)(ws + (16u << 20));
  __bf16* Vb    = (__bf16*)(ws + (32u << 20));
  __bf16* ctx   = (__bf16*)(ws + (48u << 20));
  __bf16* mid   = (__bf16*)(ws + 0);
  __bf16* aout  = (__bf16*)(ws + (64u << 20));
  __bf16* h1    = aout;
  __bf16* xb    = (__bf16*)(ws + (80u << 20));
  __bf16* Vtb   = (__bf16*)(ws + (80u << 20));
  __bf16* fout  = (__bf16*)(ws + (80u << 20));
  __bf16* WqkvT = (__bf16*)(ws + (96u << 20));
  __bf16* WoT   = (__bf16*)(ws + (96u << 20) + 3 * (1u << 21));
  __bf16* W1T   = (__bf16*)(ws + (104u << 20));
  __bf16* W2T   = (__bf16*)(ws + (112u << 20));
  float*  bqkv  = (float*)(ws + (120u << 20));
  float*  outp  = (float*)d_out;

  const dim3 blk(256);
  // ---- prep
  convert_f2b_k<<<dim3(8192), blk, 0, stream>>>(x, xb);
  transpose4_f2b_k<<<dim3(32, 32, 4), blk, 0, stream>>>(Wq, Wk, Wv, Wo, WqkvT);
  transpose_f2b_k<<<dim3(128, 32), blk, 0, stream>>>(W1, W1T, 1024, 4096);
  transpose_f2b_k<<<dim3(32, 128), blk, 0, stream>>>(W2, W2T, 4096, 1024);
  concat3_k<<<dim3(12), blk, 0, stream>>>(bq, bk, bv, bqkv);

  // ---- QKV fused projection (head-split scatter), 1536 blocks
  gemm_db<2><<<dim3(64 * 24), blk, 0, stream>>>(xb, WqkvT, bqkv, Qb,
                                                8192, 3072, 1024);
  // ---- V -> V^T per (b,h)
  transpose_v_k<<<dim3(32, 2, 128), blk, 0, stream>>>(Vb, Vtb);
  // ---- attention
  attn_kernel<<<dim3(4, 128), blk, 0, stream>>>(Qb, Kb, Vtb, ctx);
  // ---- output projection, 512 blocks
  gemm_db<0><<<dim3(64 * 8), blk, 0, stream>>>(ctx, WoT, bo, aout,
                                               8192, 1024, 1024);
  // ---- h1 = LN(x + attn_out)
  add_ln_kernel<float, __bf16, __bf16><<<dim3(8192), blk, 0, stream>>>(
      x, aout, g1, be1, h1);
  // ---- FFN
  gemm_db<1><<<dim3(64 * 32), blk, 0, stream>>>(h1, W1T, b1, mid,
                                                8192, 4096, 1024);
  gemm_db<0><<<dim3(64 * 8), blk, 0, stream>>>(mid, W2T, b2, fout,
                                               8192, 1024, 4096);
  // ---- out = LN(h1 + ffn)
  add_ln_kernel<__bf16, __bf16, float><<<dim3(8192), blk, 0, stream>>>(
      h1, fout, g3, be3, outp);
}

// Round 11
// 443.041 us; speedup vs baseline: 1.0963x; 1.0669x over previous
//
#include <hip/hip_runtime.h>
#include <hip/hip_bf16.h>

typedef __bf16 bf16x8 __attribute__((ext_vector_type(8)));
typedef __bf16 bf16x4 __attribute__((ext_vector_type(4)));
typedef float f32x4 __attribute__((ext_vector_type(4)));

#define GLOBAL_LOAD_LDS16(gp, lp)                                              \
  __builtin_amdgcn_global_load_lds(                                            \
      (const __attribute__((address_space(1))) void*)(gp),                     \
      (__attribute__((address_space(3))) void*)(lp), 16, 0, 0)

// ---------------------------------------------------------------------------
// Prep kernels (one-time, bandwidth-bound)
// ---------------------------------------------------------------------------
__global__ __launch_bounds__(256) void transpose4_f2b_k(
    const float* __restrict__ s0, const float* __restrict__ s1,
    const float* __restrict__ s2, const float* __restrict__ s3,
    __bf16* __restrict__ dst) {
  __shared__ float tile[32][33];
  const float* srcs[4] = {s0, s1, s2, s3};
  const float* src = srcs[blockIdx.z];
  __bf16* d = dst + ((size_t)blockIdx.z << 20);
  const int bx = blockIdx.x * 32, by = blockIdx.y * 32;
  const int tx = threadIdx.x & 31, ty = threadIdx.x >> 5;
#pragma unroll
  for (int i = 0; i < 32; i += 8)
    tile[ty + i][tx] = src[(size_t)(by + ty + i) * 1024 + bx + tx];
  __syncthreads();
#pragma unroll
  for (int i = 0; i < 32; i += 8)
    d[(size_t)(bx + ty + i) * 1024 + by + tx] = (__bf16)tile[tx][ty + i];
}

__global__ __launch_bounds__(256) void transpose_f2b_k(
    const float* __restrict__ src, __bf16* __restrict__ dst, int R, int C) {
  __shared__ float tile[32][33];
  const int bx = blockIdx.x * 32, by = blockIdx.y * 32;
  const int tx = threadIdx.x & 31, ty = threadIdx.x >> 5;
#pragma unroll
  for (int i = 0; i < 32; i += 8)
    tile[ty + i][tx] = src[(size_t)(by + ty + i) * C + bx + tx];
  __syncthreads();
#pragma unroll
  for (int i = 0; i < 32; i += 8)
    dst[(size_t)(bx + ty + i) * R + by + tx] = (__bf16)tile[tx][ty + i];
}

// batched bf16 transpose: per bh, [1024 s][64 d] -> [64 d][1024 s]
__global__ __launch_bounds__(256) void transpose_v_k(
    const __bf16* __restrict__ src, __bf16* __restrict__ dst) {
  __shared__ __bf16 tile[32][33];
  const int bh = blockIdx.z;
  const int s0 = blockIdx.x * 32, d0 = blockIdx.y * 32;
  const size_t base = (size_t)bh << 16;
  const int tx = threadIdx.x & 31, ty = threadIdx.x >> 5;
#pragma unroll
  for (int i = 0; i < 32; i += 8)
    tile[ty + i][tx] = src[base + (size_t)(s0 + ty + i) * 64 + d0 + tx];
  __syncthreads();
#pragma unroll
  for (int i = 0; i < 32; i += 8)
    dst[base + (size_t)(d0 + ty + i) * 1024 + s0 + tx] = tile[tx][ty + i];
}

__global__ __launch_bounds__(256) void convert_f2b_k(const float* __restrict__ s,
                                                     __bf16* __restrict__ d) {
  const size_t i = ((size_t)blockIdx.x * 256 + threadIdx.x) * 4;
  const float4 v = *(const float4*)(s + i);
  bf16x4 o;
  o[0] = (__bf16)v.x; o[1] = (__bf16)v.y; o[2] = (__bf16)v.z; o[3] = (__bf16)v.w;
  *(bf16x4*)(d + i) = o;
}

__global__ void concat3_k(const float* a, const float* b, const float* c,
                          float* o) {
  int i = blockIdx.x * 256 + threadIdx.x;
  if (i < 1024) o[i] = a[i];
  else if (i < 2048) o[i] = b[i - 1024];
  else if (i < 3072) o[i] = c[i - 2048];
}

// ---------------------------------------------------------------------------
// Staging macro: one wave stages 16 rows (2x8) of a [64.. x 64] bf16 region,
// linear LDS dest, pre-swizzled global source chunk (c ^= r&7).
// ---------------------------------------------------------------------------
#define STG(P, rowbase, Kld, kbase, DST)                                       \
  do {                                                                         \
    GLOBAL_LOAD_LDS16((P) + (size_t)((rowbase) + wave * 16 + srow) * (Kld) +   \
                          (kbase) + sch8,                                      \
                      (DST) + wave * 1024);                                    \
    GLOBAL_LOAD_LDS16((P) + (size_t)((rowbase) + wave * 16 + 8 + srow) *       \
                              (Kld) + (kbase) + sch8,                          \
                      (DST) + wave * 1024 + 512);                              \
  } while (0)

// ---------------------------------------------------------------------------
// gemm_db: C[M,N] = A @ Bt^T + bias. BM=BN=128, BK=64.  ROUND-8 VERIFIED
// BEST (FFN1 78.7us / 873 TF; FETCH 139->65 MB via supertile). Loop order
// is load-bearing (round-10 lesson): ds_reads FIRST (read port clear),
// THEN stage t+1 (returns land during the MFMA window when the LDS write
// port is idle), then MFMA, vmcnt(0), barrier. Stage-first regressed 18%
// (write-port returns collide with the read burst that gates MFMAs).
//   [16 ds_read (buf cur) | 8 global_load_lds (t+1 -> buf nxt) | setprio1 |
//    32 MFMA | setprio0 | vmcnt(0) | s_barrier | swap]
// 256 threads / 4 waves as 2M x 2N (wave tile 64x64). Double-buffered LDS
// (64 KiB -> 2 blocks/CU, 16 waves/CU); co-resident block absorbs stalls
// (m114). Supertile+XCD block map (round-8 verified).
// EPI: 0 plain, 1 ReLU, 2 QKV head-split scatter (N==3072)
// ---------------------------------------------------------------------------
template <int EPI>
__global__ __launch_bounds__(256, 2) void gemm_db(const __bf16* __restrict__ A,
                                                  const __bf16* __restrict__ Bt,
                                                  const float* __restrict__ bias,
                                                  __bf16* __restrict__ C,
                                                  int M, int N, int K) {
  __shared__ __align__(16) __bf16 Abuf[2][128 * 64];  // 32 KiB
  __shared__ __align__(16) __bf16 Bbuf[2][128 * 64];  // 32 KiB
  const int tid = threadIdx.x;
  const int wave = tid >> 6, lane = tid & 63;
  const int quad = lane >> 4, l15 = lane & 15;
  const int wm = wave >> 1, wn = wave & 1;  // 2M x 2N

  // XCD-aware bijective swizzle (nwg % 8 == 0 for all launches), then
  // 8x8-tile supertile mapping within each XCD's contiguous wg range.
  const int nwg = gridDim.x;
  const int cpx = nwg >> 3;
  const int bid = blockIdx.x;
  const int wg = (bid & 7) * cpx + (bid >> 3);
  const int gy = N >> 7;
  const int nstc = gy >> 3;              // supertile columns
  const int st = wg >> 6;                // supertile index (row-major)
  const int r = wg & 63;                 // block within supertile
  const int stm = st / nstc, stn = st - stm * nstc;
  const int tm = (stm << 3) + (r >> 3);
  const int tn = (stn << 3) + (r & 7);
  const int m0 = tm << 7, n0 = tn << 7;

  const int srow = lane >> 3;
  const int sch8 = ((lane & 7) ^ srow) * 8;      // pre-swizzled source chunk
  const int aoff = (wm * 64 + l15) * 64;         // A row base in [128][64]
  const int boff = (wn * 64 + l15) * 64;         // B row base in [128][64]
  const int c0 = (quad ^ (l15 & 7)) * 8;         // swizzled k-chunk (kh=0)

  bf16x8 af[4][2], bfr[4][2];
  f32x4 acc[4][4] = {};  // [f (A frag)][g (B frag)]

  const int NT = K >> 6;

  const __bf16* a_c = Abuf[0];
  const __bf16* a_n = Abuf[1];
  const __bf16* b_c = Bbuf[0];
  const __bf16* b_n = Bbuf[1];

  // prologue: stage tile 0 into buf0 (8 loads/wave-group), drain, publish.
  STG(A, m0, K, 0, (__bf16*)a_c);
  STG(A, m0 + 64, K, 0, (__bf16*)a_c + 64 * 64);
  STG(Bt, n0, K, 0, (__bf16*)b_c);
  STG(Bt, n0 + 64, K, 0, (__bf16*)b_c + 64 * 64);
  asm volatile("s_waitcnt vmcnt(0)" ::: "memory");
  __builtin_amdgcn_s_barrier();
  asm volatile("" ::: "memory");

  for (int t = 0; t < NT; ++t) {
    // current-tile fragment reads FIRST (round-8 order; load-bearing)
#pragma unroll
    for (int f = 0; f < 4; ++f) {
      af[f][0] = *(const bf16x8*)(a_c + aoff + f * 1024 + c0);
      af[f][1] = *(const bf16x8*)(a_c + aoff + f * 1024 + (c0 ^ 32));
    }
#pragma unroll
    for (int g = 0; g < 4; ++g) {
      bfr[g][0] = *(const bf16x8*)(b_c + boff + g * 1024 + c0);
      bfr[g][1] = *(const bf16x8*)(b_c + boff + g * 1024 + (c0 ^ 32));
    }
    // stage tile t+1 into the other buffer
    const int kn = (t + 1) << 6;
    const bool pf = (t + 1 < NT);
    if (pf) {
      STG(A, m0, K, kn, (__bf16*)a_n);
      STG(A, m0 + 64, K, kn, (__bf16*)a_n + 64 * 64);
      STG(Bt, n0, K, kn, (__bf16*)b_n);
      STG(Bt, n0 + 64, K, kn, (__bf16*)b_n + 64 * 64);
    }
    __builtin_amdgcn_s_setprio(1);
#pragma unroll
    for (int f = 0; f < 4; ++f)
#pragma unroll
      for (int g = 0; g < 4; ++g) {
        acc[f][g] = __builtin_amdgcn_mfma_f32_16x16x32_bf16(
            af[f][0], bfr[g][0], acc[f][g], 0, 0, 0);
        acc[f][g] = __builtin_amdgcn_mfma_f32_16x16x32_bf16(
            af[f][1], bfr[g][1], acc[f][g], 0, 0, 0);
      }
    __builtin_amdgcn_s_setprio(0);
    if (pf) {
      asm volatile("s_waitcnt vmcnt(0)" ::: "memory");
      __builtin_amdgcn_s_barrier();
      asm volatile("" ::: "memory");
    }
    // swap buffers
    const __bf16* ta = a_c; a_c = a_n; a_n = ta;
    const __bf16* tb = b_c; b_c = b_n; b_n = tb;
  }

  // epilogue: D layout col=l15, row=quad*4+i within each 16x16 frag
  float bvv[4];
#pragma unroll
  for (int g = 0; g < 4; ++g) bvv[g] = bias[n0 + wn * 64 + g * 16 + l15];
#pragma unroll
  for (int f = 0; f < 4; ++f)
#pragma unroll
    for (int i = 0; i < 4; ++i) {
      const int row = m0 + wm * 64 + f * 16 + quad * 4 + i;
#pragma unroll
      for (int g = 0; g < 4; ++g) {
        const int col = n0 + wn * 64 + g * 16 + l15;
        float v = acc[f][g][i] + bvv[g];
        if (EPI == 1) v = fmaxf(v, 0.0f);
        size_t oidx;
        if (EPI == 2) {
          const int which = col >> 10, wi = col & 1023;
          const int h = wi >> 6, d = wi & 63;
          const int b = row >> 10, s = row & 1023;
          oidx = ((size_t)which << 23) +
                 (((size_t)(b * 16 + h) << 16) + s * 64 + d);
        } else {
          oidx = (size_t)row * N + col;
        }
        C[oidx] = (__bf16)v;
      }
    }
}

// ---------------------------------------------------------------------------
// Flash attention: causal strict, row 0 zeroed. setprio (T5, m191) around
// QK^T and PV MFMA clusters (kept from round 10 — net positive there).
// ---------------------------------------------------------------------------
__global__ __launch_bounds__(256) void attn_kernel(const __bf16* __restrict__ Q,
                                                   const __bf16* __restrict__ Kg,
                                                   const __bf16* __restrict__ Vt,
                                                   __bf16* __restrict__ ctx) {
  const int qp = blockIdx.x;   // 0..3
  const int bh = blockIdx.y;   // 0..127
  const int b = bh >> 4, h = bh & 15;
  const int tid = threadIdx.x, wave = tid >> 6, lane = tid & 63;
  const int quad = lane >> 4, l15 = lane & 15;
  const size_t hoff = (size_t)bh << 16;
  const __bf16* Qh = Q + hoff;
  const __bf16* Kh = Kg + hoff;
  const __bf16* Vh = Vt + hoff;

  __shared__ __align__(16) __bf16 Ks[64 * 64];
  __shared__ __align__(16) __bf16 Vs[64 * 64];
  __shared__ __align__(16) __bf16 Ps[4][32 * 72];
  __shared__ float lL[128];

  const int skey = wave * 8 + (lane >> 3);
  const int sgr = lane & 7;

#pragma unroll
  for (int pass = 0; pass < 2; ++pass) {
    const int qt = pass ? (7 - qp) : qp;
    const int qb = qt * 128;

    bf16x8 qf[2][2];
#pragma unroll
    for (int g = 0; g < 2; ++g) {
      const int qrow = qb + wave * 32 + g * 16 + l15;
      bf16x8 t0 = *(const bf16x8*)(Qh + (size_t)qrow * 64 + quad * 8);
      bf16x8 t1 = *(const bf16x8*)(Qh + (size_t)qrow * 64 + 32 + quad * 8);
#pragma unroll
      for (int e = 0; e < 8; ++e) {
        qf[g][0][e] = (__bf16)((float)t0[e] * 0.125f);
        qf[g][1][e] = (__bf16)((float)t1[e] * 0.125f);
      }
    }

    f32x4 oacc[4][2] = {};
    float lrun[2][4] = {};

    const int ktmax = 2 * qt + 1;
    for (int kt = 0; kt <= ktmax; ++kt) {
      __syncthreads();
#pragma unroll
      for (int j = 0; j < 2; ++j) {
        const int row = skey + 32 * j;
        GLOBAL_LOAD_LDS16(
            Kh + (size_t)(kt * 64 + row) * 64 + ((sgr ^ (row & 7)) * 8),
            Ks + j * 2048 + wave * 512);
        GLOBAL_LOAD_LDS16(
            Vh + (size_t)row * 1024 + kt * 64 + ((sgr ^ (row & 7)) * 8),
            Vs + j * 2048 + wave * 512);
      }
      __syncthreads();

      f32x4 sacc[2][4] = {};
      __builtin_amdgcn_s_setprio(1);
#pragma unroll
      for (int nt = 0; nt < 4; ++nt) {
        const int key = nt * 16 + l15, sw = key & 7;
        bf16x8 kf0 = *(const bf16x8*)(Ks + key * 64 + ((quad ^ sw) * 8));
        bf16x8 kf1 = *(const bf16x8*)(Ks + key * 64 + (((quad + 4) ^ sw) * 8));
#pragma unroll
        for (int g = 0; g < 2; ++g) {
          sacc[g][nt] = __builtin_amdgcn_mfma_f32_16x16x32_bf16(
              qf[g][0], kf0, sacc[g][nt], 0, 0, 0);
          sacc[g][nt] = __builtin_amdgcn_mfma_f32_16x16x32_bf16(
              qf[g][1], kf1, sacc[g][nt], 0, 0, 0);
        }
      }
      __builtin_amdgcn_s_setprio(0);

      const bool tilemask = (kt >= 2 * qt);
#pragma unroll
      for (int g = 0; g < 2; ++g)
#pragma unroll
        for (int nt = 0; nt < 4; ++nt) {
          const int key = kt * 64 + nt * 16 + l15;
#pragma unroll
          for (int r = 0; r < 4; ++r) {
            float p = __expf(fminf(sacc[g][nt][r], 60.0f));
            if (tilemask && key >= qb + wave * 32 + g * 16 + quad * 4 + r)
              p = 0.0f;
            sacc[g][nt][r] = p;
            lrun[g][r] += p;
          }
        }

#pragma unroll
      for (int g = 0; g < 2; ++g)
#pragma unroll
        for (int nt = 0; nt < 4; ++nt)
#pragma unroll
          for (int r = 0; r < 4; ++r)
            Ps[wave][(g * 16 + quad * 4 + r) * 72 + nt * 16 + l15] =
                (__bf16)sacc[g][nt][r];

#pragma unroll
      for (int kc = 0; kc < 2; ++kc) {
        bf16x8 pf[2];
#pragma unroll
        for (int g = 0; g < 2; ++g)
          pf[g] = *(const bf16x8*)(&Ps[wave][(g * 16 + l15) * 72 + kc * 32 +
                                             quad * 8]);
        __builtin_amdgcn_s_setprio(1);
#pragma unroll
        for (int mdt = 0; mdt < 4; ++mdt) {
          const int d = mdt * 16 + l15, sw = d & 7;
          bf16x8 vf =
              *(const bf16x8*)(Vs + d * 64 + (((kc * 4 + quad) ^ sw) * 8));
#pragma unroll
          for (int g = 0; g < 2; ++g)
            oacc[mdt][g] = __builtin_amdgcn_mfma_f32_16x16x32_bf16(
                vf, pf[g], oacc[mdt][g], 0, 0, 0);
        }
        __builtin_amdgcn_s_setprio(0);
      }
    }

#pragma unroll
    for (int g = 0; g < 2; ++g)
#pragma unroll
      for (int r = 0; r < 4; ++r) {
        float s = lrun[g][r];
#pragma unroll
        for (int d = 1; d < 16; d <<= 1) s += __shfl_xor(s, d);
        if (l15 == 0) lL[wave * 32 + g * 16 + quad * 4 + r] = s;
      }
    float linv[2];
#pragma unroll
    for (int g = 0; g < 2; ++g) {
      const float l = lL[wave * 32 + g * 16 + l15];
      linv[g] = (qb + wave * 32 + g * 16 + l15 == 0) ? 0.0f : (1.0f / l);
    }
    __bf16* Ot = Ps[wave];
#pragma unroll
    for (int mdt = 0; mdt < 4; ++mdt)
#pragma unroll
      for (int g = 0; g < 2; ++g)
#pragma unroll
        for (int r = 0; r < 4; ++r)
          Ot[(g * 16 + l15) * 72 + mdt * 16 + quad * 4 + r] =
              (__bf16)(oacc[mdt][g][r] * linv[g]);
#pragma unroll
    for (int rr = 0; rr < 2; ++rr)
#pragma unroll
      for (int j = 0; j < 2; ++j) {
        const int row = rr * 16 + (lane >> 2), chk = (lane & 3) + 4 * j;
        bf16x8 ov = *(const bf16x8*)(Ot + row * 72 + chk * 8);
        const size_t oi = ((size_t)(b * 1024 + qb + wave * 32 + row)) * 1024 +
                          h * 64 + chk * 8;
        *(bf16x8*)(ctx + oi) = ov;
      }
  }
}

// ---------------------------------------------------------------------------
// out = LayerNorm(x + y) * g + beta ; rows of 1024, one block per row.
// ---------------------------------------------------------------------------
template <typename TX, typename TY, typename TO>
__global__ __launch_bounds__(256) void add_ln_kernel(const TX* __restrict__ x,
                                                     const TY* __restrict__ y,
                                                     const float* __restrict__ g,
                                                     const float* __restrict__ be,
                                                     TO* __restrict__ out) {
  const int row = blockIdx.x;
  const size_t base = (size_t)row * 1024;
  const int t = threadIdx.x;
  float xv[4], yv[4];
  if constexpr (sizeof(TX) == 4) {
    const float4 a = *(const float4*)(x + base + t * 4);
    xv[0] = a.x; xv[1] = a.y; xv[2] = a.z; xv[3] = a.w;
  } else {
    const bf16x4 a = *(const bf16x4*)(x + base + t * 4);
#pragma unroll
    for (int i = 0; i < 4; ++i) xv[i] = (float)a[i];
  }
  if constexpr (sizeof(TY) == 4) {
    const float4 a = *(const float4*)(y + base + t * 4);
    yv[0] = a.x; yv[1] = a.y; yv[2] = a.z; yv[3] = a.w;
  } else {
    const bf16x4 a = *(const bf16x4*)(y + base + t * 4);
#pragma unroll
    for (int i = 0; i < 4; ++i) yv[i] = (float)a[i];
  }
  float v[4], s = 0.0f, s2 = 0.0f;
#pragma unroll
  for (int i = 0; i < 4; ++i) {
    v[i] = xv[i] + yv[i];
    s += v[i];
    s2 += v[i] * v[i];
  }
#pragma unroll
  for (int m = 1; m < 64; m <<= 1) {
    s += __shfl_xor(s, m);
    s2 += __shfl_xor(s2, m);
  }
  __shared__ float ss[4], ss2[4];
  const int w = t >> 6;
  if ((t & 63) == 0) { ss[w] = s; ss2[w] = s2; }
  __syncthreads();
  s = ss[0] + ss[1] + ss[2] + ss[3];
  s2 = ss2[0] + ss2[1] + ss2[2] + ss2[3];
  const float mu = s * (1.0f / 1024.0f);
  const float var = s2 * (1.0f / 1024.0f) - mu * mu;
  const float rstd = rsqrtf(var + 1e-5f);
#pragma unroll
  for (int i = 0; i < 4; ++i) {
    const float o = (v[i] - mu) * rstd * g[t * 4 + i] + be[t * 4 + i];
    out[base + t * 4 + i] = (TO)o;
  }
}

// ---------------------------------------------------------------------------
extern "C" void kernel_launch(void* const* d_in, const int* in_sizes, int n_in,
                              void* d_out, int out_size, void* d_ws,
                              size_t ws_size, hipStream_t stream) {
  (void)in_sizes; (void)n_in; (void)out_size; (void)ws_size;
  const float* x   = (const float*)d_in[0];
  const float* Wq  = (const float*)d_in[1];
  const float* bq  = (const float*)d_in[2];
  const float* Wk  = (const float*)d_in[3];
  const float* bk  = (const float*)d_in[4];
  const float* Wv  = (const float*)d_in[5];
  const float* bv  = (const float*)d_in[6];
  const float* Wo  = (const float*)d_in[7];
  const float* bo  = (const float*)d_in[8];
  const float* W1  = (const float*)d_in[9];
  const float* b1  = (const float*)d_in[10];
  const float* W2  = (const float*)d_in[11];
  const float* b2  = (const float*)d_in[12];
  const float* g1  = (const float*)d_in[13];
  const float* be1 = (const float*)d_in[14];
  const float* g3  = (const float*)d_in[15];
  const float* be3 = (const float*)d_in[16];

  char* ws = (char*)d_ws;
  __bf16* Qb    = (__bf16*)(ws + 0);
  __bf16* Kb    = (__bf16*)(ws + (16u << 20));
  __bf16* Vb    = (__bf16*)(ws + (32u << 20));
  __bf16* ctx   = (__bf16*)(ws + (48u << 20));
  __bf16* mid   = (__bf16*)(ws + 0);
  __bf16* aout  = (__bf16*)(ws + (64u << 20));
  __bf16* h1    = aout;
  __bf16* xb    = (__bf16*)(ws + (80u << 20));
  __bf16* Vtb   = (__bf16*)(ws + (80u << 20));
  __bf16* fout  = (__bf16*)(ws + (80u << 20));
  __bf16* WqkvT = (__bf16*)(ws + (96u << 20));
  __bf16* WoT   = (__bf16*)(ws + (96u << 20) + 3 * (1u << 21));
  __bf16* W1T   = (__bf16*)(ws + (104u << 20));
  __bf16* W2T   = (__bf16*)(ws + (112u << 20));
  float*  bqkv  = (float*)(ws + (120u << 20));
  float*  outp  = (float*)d_out;

  const dim3 blk(256);
  // ---- prep
  convert_f2b_k<<<dim3(8192), blk, 0, stream>>>(x, xb);
  transpose4_f2b_k<<<dim3(32, 32, 4), blk, 0, stream>>>(Wq, Wk, Wv, Wo, WqkvT);
  transpose_f2b_k<<<dim3(128, 32), blk, 0, stream>>>(W1, W1T, 1024, 4096);
  transpose_f2b_k<<<dim3(32, 128), blk, 0, stream>>>(W2, W2T, 4096, 1024);
  concat3_k<<<dim3(12), blk, 0, stream>>>(bq, bk, bv, bqkv);

  // ---- QKV fused projection (head-split scatter), 1536 blocks
  gemm_db<2><<<dim3(64 * 24), blk, 0, stream>>>(xb, WqkvT, bqkv, Qb,
                                                8192, 3072, 1024);
  // ---- V -> V^T per (b,h)
  transpose_v_k<<<dim3(32, 2, 128), blk, 0, stream>>>(Vb, Vtb);
  // ---- attention
  attn_kernel<<<dim3(4, 128), blk, 0, stream>>>(Qb, Kb, Vtb, ctx);
  // ---- output projection, 512 blocks
  gemm_db<0><<<dim3(64 * 8), blk, 0, stream>>>(ctx, WoT, bo, aout,
                                               8192, 1024, 1024);
  // ---- h1 = LN(x + attn_out)
  add_ln_kernel<float, __bf16, __bf16><<<dim3(8192), blk, 0, stream>>>(
      x, aout, g1, be1, h1);
  // ---- FFN
  gemm_db<1><<<dim3(64 * 32), blk, 0, stream>>>(h1, W1T, b1, mid,
                                                8192, 4096, 1024);
  gemm_db<0><<<dim3(64 * 8), blk, 0, stream>>>(mid, W2T, b2, fout,
                                               8192, 1024, 4096);
  // ---- out = LN(h1 + ffn)
  add_ln_kernel<__bf16, __bf16, float><<<dim3(8192), blk, 0, stream>>>(
      h1, fout, g3, be3, outp);
}